// Round 3
// baseline (215.392 us; speedup 1.0000x reference)
//
#include <hip/hip_runtime.h>

typedef _Float16 f16;
typedef _Float16 f16x8 __attribute__((ext_vector_type(8)));
typedef float f32x4 __attribute__((ext_vector_type(4)));

#define NB 5
#define H 64
#define DIN 100
#define NT 256
#define MAIN_BLOCKS 768

// packed weight-fragment regions in d_ws, units of 16B frags
#define FR_W1   0      // 4 ksteps * 4 mtiles * 64 lanes = 1024 frags
#define FR_W2   1024   // 2 * 4 * 64 = 512
#define FR_HD   1536   // (q*2+layer)*512 + (s*4+mt)*64 + lane ; 5*2*512 = 5120
#define FR_TOT  6656

// Pack weights into MFMA A-operand fragment layout for the transposed compute:
// A = W^T tile: lane l holds W[k=32s+8*(l>>4)+e][16*mt + (l&15)], e=0..7.
__global__ __launch_bounds__(256)
void prepack_kernel(const float* __restrict__ dW1, const float* __restrict__ dW2,
                    const float* __restrict__ hw1, const float* __restrict__ hw2,
                    f16x8* __restrict__ pw)
{
    int F = blockIdx.x * 256 + threadIdx.x;
    if (F >= FR_TOT) return;
    int lane = F & 63, g = lane >> 4, c = lane & 15;
    const float* src;
    int s, mt, kmax;
    if (F < FR_W2) {                       // trunk W1 [100][64], zero-pad K to 128
        int r = F; s = r >> 8; mt = (r >> 6) & 3; src = dW1; kmax = 100;
    } else if (F < FR_HD) {                // trunk W2 [64][64]
        int r = F - FR_W2; s = r >> 8; mt = (r >> 6) & 3; src = dW2; kmax = 64;
    } else {                               // heads hw1/hw2 [5][64][64]
        int r = F - FR_HD; int ql = r >> 9; int q = ql >> 1; int l = ql & 1;
        int r2 = r & 511; s = r2 >> 8; mt = (r2 >> 6) & 3;
        src = (l ? hw2 : hw1) + q * 64 * 64; kmax = 64;
    }
    f16x8 v;
    #pragma unroll
    for (int e = 0; e < 8; ++e) {
        int k = 32 * s + 8 * g + e;
        int m = 16 * mt + c;
        float val = (k < kmax) ? src[k * 64 + m] : 0.0f;
        v[e] = (f16)val;
    }
    pw[F] = v;
}

__device__ __forceinline__ f32x4 mfma16(f16x8 a, f16x8 b, f32x4 c) {
    return __builtin_amdgcn_mfma_f32_16x16x32_f16(a, b, c, 0, 0, 0);
}

__global__ __launch_bounds__(NT, 3)
void drnet_main(const float* __restrict__ t, const float* __restrict__ x,
                const float* __restrict__ db1, const float* __restrict__ db2,
                const float* __restrict__ hb1, const float* __restrict__ htw1,
                const float* __restrict__ hb2, const float* __restrict__ htw2,
                const float* __restrict__ hw3, const float* __restrict__ htw3,
                const float* __restrict__ hb3,
                const f16x8* __restrict__ pw,
                float* __restrict__ out, int N, int nch)
{
    __shared__ float sb1f[H], sb2f[H];
    __shared__ float shb1[NB * H], shw1t[NB * H], shb2[NB * H], shw2t[NB * H], sw3f[NB * H];
    __shared__ float shtw3[NB], shb3[NB];
    __shared__ unsigned char sli[NT], sqv[NT];
    __shared__ float stv[NT];
    __shared__ float sout[NT];
    __shared__ int scnt[NB + 1], sbase[NB + 1];
    __shared__ __align__(16) unsigned char hbuf[4][2][2048];  // per-wave [16][64] f16, XOR-swizzled

    const int tid = threadIdx.x;
    const int lane = tid & 63;
    const int wv = tid >> 6;
    const int g = lane >> 4;
    const int row = lane & 15;

    // one-time per block: stage fp32 biases/t-weights/w3 into LDS
    for (int p = tid; p < H; p += NT) { sb1f[p] = db1[p]; sb2f[p] = db2[p]; }
    for (int p = tid; p < NB * H; p += NT) {
        shb1[p] = hb1[p];  shw1t[p] = htw1[p];
        shb2[p] = hb2[p];  shw2t[p] = htw2[p];
        sw3f[p] = hw3[p];
    }
    if (tid < NB) { shtw3[tid] = htw3[tid]; shb3[tid] = hb3[tid]; }

    // hoist trunk weight frags into registers (48 VGPR, reused every tile)
    f16x8 w1f[16], w2f[8];
    #pragma unroll
    for (int u = 0; u < 16; ++u) w1f[u] = pw[FR_W1 + u * 64 + lane];
    #pragma unroll
    for (int u = 0; u < 8; ++u)  w2f[u] = pw[FR_W2 + u * 64 + lane];

    for (int ch = blockIdx.x; ch < nch; ch += MAIN_BLOCKS) {
        if (tid <= NB) scnt[tid] = 0;
        __syncthreads();
        const int i0 = ch * NT + tid;
        int q0 = NB; float tv0 = 0.f;
        if (i0 < N) {
            tv0 = t[i0];
            q0 = min((int)(tv0 * 5.0f), NB - 1);   // t in [0,1): trunc == floor, >=0
        }
        int pos = atomicAdd(&scnt[q0], 1);
        __syncthreads();
        if (tid == 0) {
            int r = 0;
            #pragma unroll
            for (int b = 0; b <= NB; ++b) { sbase[b] = r; r += scnt[b]; }
        }
        __syncthreads();
        int sp = sbase[q0] + pos;
        sli[sp] = (unsigned char)tid; sqv[sp] = (unsigned char)q0; stv[sp] = tv0;
        __syncthreads();

        // ---- prefetch tile 0's x rows into registers ----
        float4 xr[7];
        {
            int pp = (wv * 4) * 16 + row;
            int ivn = (sqv[pp] < NB) ? (ch * NT + sli[pp]) : (ch * NT);
            const float4* x4 = (const float4*)(x + (size_t)ivn * DIN);
            #pragma unroll
            for (int s = 0; s < 3; ++s) { xr[2*s] = x4[8*s + 2*g]; xr[2*s+1] = x4[8*s + 2*g + 1]; }
            xr[6] = x4[24];
        }

        // wave wv owns sorted tiles 4wv..4wv+3 (16 rows each)
        for (int j = 0; j < 4; ++j) {
            const int p0 = (wv * 4 + j) * 16;
            const int qlo = sqv[p0];
            const int qhi = (qlo < NB) ? min((int)sqv[p0 + 15], NB - 1) : 0;
            const int li = sli[p0 + row];
            const int rq = sqv[p0 + row];
            const float rt = stv[p0 + row];

            // ---- convert raw regs -> A-frags (frees xr for next prefetch) ----
            f16x8 xf[4];
            #pragma unroll
            for (int s = 0; s < 3; ++s) {
                float4 a = xr[2*s], b = xr[2*s+1];
                xf[s][0] = (f16)a.x; xf[s][1] = (f16)a.y; xf[s][2] = (f16)a.z; xf[s][3] = (f16)a.w;
                xf[s][4] = (f16)b.x; xf[s][5] = (f16)b.y; xf[s][6] = (f16)b.z; xf[s][7] = (f16)b.w;
            }
            {
                float4 a = xr[6];
                const bool lo = (g == 0);            // k=96..99 valid only for g==0
                xf[3][0] = lo ? (f16)a.x : (f16)0.f; xf[3][1] = lo ? (f16)a.y : (f16)0.f;
                xf[3][2] = lo ? (f16)a.z : (f16)0.f; xf[3][3] = lo ? (f16)a.w : (f16)0.f;
                xf[3][4] = (f16)0.f; xf[3][5] = (f16)0.f; xf[3][6] = (f16)0.f; xf[3][7] = (f16)0.f;
            }

            // ---- issue next tile's x loads now; latency hides under this tile's compute ----
            if (j < 3) {
                int pp = (wv * 4 + j + 1) * 16 + row;
                int ivn = (sqv[pp] < NB) ? (ch * NT + sli[pp]) : (ch * NT);
                const float4* x4 = (const float4*)(x + (size_t)ivn * DIN);
                #pragma unroll
                for (int s = 0; s < 3; ++s) { xr[2*s] = x4[8*s + 2*g]; xr[2*s+1] = x4[8*s + 2*g + 1]; }
                xr[6] = x4[24];
            }

            if (qlo >= NB) continue;                  // whole tile is padding

            const f32x4 zero = {0.f, 0.f, 0.f, 0.f};

            // ---- trunk L1: h1^T = W1^T x^T ----
            f32x4 acc[4] = {zero, zero, zero, zero};
            #pragma unroll
            for (int s = 0; s < 4; ++s)
                #pragma unroll
                for (int mt = 0; mt < 4; ++mt)
                    acc[mt] = mfma16(w1f[s * 4 + mt], xf[s], acc[mt]);

            unsigned char* hA = hbuf[wv][0];
            unsigned char* hB = hbuf[wv][1];
            #pragma unroll
            for (int mt = 0; mt < 4; ++mt) {
                const float* bb = &sb1f[16 * mt + 4 * g];
                union { f16 h[4]; unsigned long long u; } pk;
                #pragma unroll
                for (int r2 = 0; r2 < 4; ++r2) pk.h[r2] = (f16)fmaxf(acc[mt][r2] + bb[r2], 0.f);
                *(unsigned long long*)(hA + ((row * 128 + 32 * mt + 8 * g) ^ ((row & 7) << 4))) = pk.u;
            }

            // ---- trunk L2: h2^T = W2^T h1^T ----
            f32x4 acc2[4] = {zero, zero, zero, zero};
            #pragma unroll
            for (int s = 0; s < 2; ++s) {
                f16x8 hf = *(const f16x8*)(hA + ((row * 128 + 64 * s + 16 * g) ^ ((row & 7) << 4)));
                #pragma unroll
                for (int mt = 0; mt < 4; ++mt)
                    acc2[mt] = mfma16(w2f[s * 4 + mt], hf, acc2[mt]);
            }
            #pragma unroll
            for (int mt = 0; mt < 4; ++mt) {
                const float* bb = &sb2f[16 * mt + 4 * g];
                union { f16 h[4]; unsigned long long u; } pk;
                #pragma unroll
                for (int r2 = 0; r2 < 4; ++r2) pk.h[r2] = (f16)fmaxf(acc2[mt][r2] + bb[r2], 0.f);
                *(unsigned long long*)(hB + ((row * 128 + 32 * mt + 8 * g) ^ ((row & 7) << 4))) = pk.u;
            }

            // ---- heads (usually 1; >1 only at sorted-bucket boundary tiles) ----
            #pragma unroll 1
            for (int q = qlo; q <= qhi; ++q) {
                const f16x8* ph1 = pw + FR_HD + (q * 2 + 0) * 512;
                const f16x8* ph2 = pw + FR_HD + (q * 2 + 1) * 512;

                f32x4 a1[4] = {zero, zero, zero, zero};
                #pragma unroll
                for (int s = 0; s < 2; ++s) {
                    f16x8 hf = *(const f16x8*)(hB + ((row * 128 + 64 * s + 16 * g) ^ ((row & 7) << 4)));
                    #pragma unroll
                    for (int mt = 0; mt < 4; ++mt)
                        a1[mt] = mfma16(ph1[(s * 4 + mt) * 64 + lane], hf, a1[mt]);
                }
                #pragma unroll
                for (int mt = 0; mt < 4; ++mt) {
                    const float* bb = &shb1[q * 64 + 16 * mt + 4 * g];
                    const float* tw = &shw1t[q * 64 + 16 * mt + 4 * g];
                    union { f16 h[4]; unsigned long long u; } pk;
                    #pragma unroll
                    for (int r2 = 0; r2 < 4; ++r2)
                        pk.h[r2] = (f16)fmaxf(a1[mt][r2] + bb[r2] + rt * tw[r2], 0.f);
                    *(unsigned long long*)(hA + ((row * 128 + 32 * mt + 8 * g) ^ ((row & 7) << 4))) = pk.u;
                }

                f32x4 a2[4] = {zero, zero, zero, zero};
                #pragma unroll
                for (int s = 0; s < 2; ++s) {
                    f16x8 hf = *(const f16x8*)(hA + ((row * 128 + 64 * s + 16 * g) ^ ((row & 7) << 4)));
                    #pragma unroll
                    for (int mt = 0; mt < 4; ++mt)
                        a2[mt] = mfma16(ph2[(s * 4 + mt) * 64 + lane], hf, a2[mt]);
                }

                // final layer in fp32 VALU: out[row] = sum_c relu(a2)[row][c]*w3[c] + t*tw3 + b3
                float partial = 0.f;
                #pragma unroll
                for (int mt = 0; mt < 4; ++mt) {
                    const float* bb = &shb2[q * 64 + 16 * mt + 4 * g];
                    const float* tw = &shw2t[q * 64 + 16 * mt + 4 * g];
                    const float* w3 = &sw3f[q * 64 + 16 * mt + 4 * g];
                    #pragma unroll
                    for (int r2 = 0; r2 < 4; ++r2) {
                        float v = fmaxf(a2[mt][r2] + bb[r2] + rt * tw[r2], 0.f);
                        partial += v * w3[r2];
                    }
                }
                partial += __shfl_xor(partial, 16, 64);
                partial += __shfl_xor(partial, 32, 64);
                if (lane < 16 && rq == q) {
                    sout[li] = partial + rt * shtw3[q] + shb3[q];
                }
            }
        }

        __syncthreads();                 // sout complete across all waves
        {
            const int iw = ch * NT + tid;
            if (iw < N) out[iw] = sout[tid];   // coalesced flush
        }
    }
}

extern "C" void kernel_launch(void* const* d_in, const int* in_sizes, int n_in,
                              void* d_out, int out_size, void* d_ws, size_t ws_size,
                              hipStream_t stream) {
    const float* t    = (const float*)d_in[0];
    const float* x    = (const float*)d_in[1];
    const float* dW1  = (const float*)d_in[2];
    const float* db1  = (const float*)d_in[3];
    const float* dW2  = (const float*)d_in[4];
    const float* db2  = (const float*)d_in[5];
    const float* hw1  = (const float*)d_in[6];
    const float* htw1 = (const float*)d_in[7];
    const float* hb1  = (const float*)d_in[8];
    const float* hw2  = (const float*)d_in[9];
    const float* htw2 = (const float*)d_in[10];
    const float* hb2  = (const float*)d_in[11];
    const float* hw3  = (const float*)d_in[12];
    const float* htw3 = (const float*)d_in[13];
    const float* hb3  = (const float*)d_in[14];
    float* out = (float*)d_out;

    const int N = in_sizes[0];
    const int nch = (N + NT - 1) / NT;
    f16x8* pw = (f16x8*)d_ws;   // 6656 * 16 B = 104 KiB of scratch

    prepack_kernel<<<(FR_TOT + 255) / 256, 256, 0, stream>>>(dW1, dW2, hw1, hw2, pw);
    drnet_main<<<MAIN_BLOCKS, NT, 0, stream>>>(t, x, db1, db2, hb1, htw1, hb2, htw2,
                                               hw3, htw3, hb3, pw, out, N, nch);
}

// Round 4
// 160.596 us; speedup vs baseline: 1.3412x; 1.3412x over previous
//
#include <hip/hip_runtime.h>

typedef _Float16 f16;
typedef _Float16 f16x8 __attribute__((ext_vector_type(8)));
typedef float f32x4 __attribute__((ext_vector_type(4)));

#define NB 5
#define H 64
#define DIN 100
#define NT 256
#define MAIN_BLOCKS 512

// packed weight-fragment regions in d_ws, units of 16B frags
#define FR_W1   0      // 4 ksteps * 4 mtiles * 64 lanes = 1024 frags
#define FR_W2   1024   // 2 * 4 * 64 = 512
#define FR_HD   1536   // (q*2+layer)*512 + (s*4+mt)*64 + lane ; 5*2*512 = 5120
#define FR_TOT  6656

// Pack weights into MFMA A-operand fragment layout for the transposed compute:
// A = W^T tile: lane l holds W[k=32s+8*(l>>4)+e][16*mt + (l&15)], e=0..7.
__global__ __launch_bounds__(256)
void prepack_kernel(const float* __restrict__ dW1, const float* __restrict__ dW2,
                    const float* __restrict__ hw1, const float* __restrict__ hw2,
                    f16x8* __restrict__ pw)
{
    int F = blockIdx.x * 256 + threadIdx.x;
    if (F >= FR_TOT) return;
    int lane = F & 63, g = lane >> 4, c = lane & 15;
    const float* src;
    int s, mt, kmax;
    if (F < FR_W2) {                       // trunk W1 [100][64], zero-pad K to 128
        int r = F; s = r >> 8; mt = (r >> 6) & 3; src = dW1; kmax = 100;
    } else if (F < FR_HD) {                // trunk W2 [64][64]
        int r = F - FR_W2; s = r >> 8; mt = (r >> 6) & 3; src = dW2; kmax = 64;
    } else {                               // heads hw1/hw2 [5][64][64]
        int r = F - FR_HD; int ql = r >> 9; int q = ql >> 1; int l = ql & 1;
        int r2 = r & 511; s = r2 >> 8; mt = (r2 >> 6) & 3;
        src = (l ? hw2 : hw1) + q * 64 * 64; kmax = 64;
    }
    f16x8 v;
    #pragma unroll
    for (int e = 0; e < 8; ++e) {
        int k = 32 * s + 8 * g + e;
        int m = 16 * mt + c;
        float val = (k < kmax) ? src[k * 64 + m] : 0.0f;
        v[e] = (f16)val;
    }
    pw[F] = v;
}

__device__ __forceinline__ f32x4 mfma16(f16x8 a, f16x8 b, f32x4 c) {
    return __builtin_amdgcn_mfma_f32_16x16x32_f16(a, b, c, 0, 0, 0);
}

// relu(acc + bias) -> f16x4, XOR-swizzled b64 store into per-wave LDS h-buffer
__device__ __forceinline__ void epi_plain(unsigned char* buf, int row, int g,
                                          const f32x4* acc, const float* bias) {
    #pragma unroll
    for (int mt = 0; mt < 4; ++mt) {
        const float* bb = &bias[16 * mt + 4 * g];
        union { f16 h[4]; unsigned long long u; } pk;
        #pragma unroll
        for (int r2 = 0; r2 < 4; ++r2) pk.h[r2] = (f16)fmaxf(acc[mt][r2] + bb[r2], 0.f);
        *(unsigned long long*)(buf + ((row * 128 + 32 * mt + 8 * g) ^ ((row & 7) << 4))) = pk.u;
    }
}

// relu(acc + bias + rt*tw) -> f16x4, swizzled store
__device__ __forceinline__ void epi_t(unsigned char* buf, int row, int g, float rt,
                                      const f32x4* acc, const float* bias, const float* tw) {
    #pragma unroll
    for (int mt = 0; mt < 4; ++mt) {
        const float* bb = &bias[16 * mt + 4 * g];
        const float* tt = &tw[16 * mt + 4 * g];
        union { f16 h[4]; unsigned long long u; } pk;
        #pragma unroll
        for (int r2 = 0; r2 < 4; ++r2)
            pk.h[r2] = (f16)fmaxf(acc[mt][r2] + bb[r2] + rt * tt[r2], 0.f);
        *(unsigned long long*)(buf + ((row * 128 + 32 * mt + 8 * g) ^ ((row & 7) << 4))) = pk.u;
    }
}

__device__ __forceinline__ f16x8 lds_read_h(const unsigned char* buf, int row, int g, int s) {
    return *(const f16x8*)(buf + ((row * 128 + 64 * s + 16 * g) ^ ((row & 7) << 4)));
}

__global__ __launch_bounds__(NT, 2)
void drnet_main(const float* __restrict__ t, const float* __restrict__ x,
                const float* __restrict__ db1, const float* __restrict__ db2,
                const float* __restrict__ hb1, const float* __restrict__ htw1,
                const float* __restrict__ hb2, const float* __restrict__ htw2,
                const float* __restrict__ hw3, const float* __restrict__ htw3,
                const float* __restrict__ hb3,
                const f16x8* __restrict__ pw,
                float* __restrict__ out, int N, int nch)
{
    __shared__ float sb1f[H], sb2f[H];
    __shared__ float shb1[NB * H], shw1t[NB * H], shb2[NB * H], shw2t[NB * H], sw3f[NB * H];
    __shared__ float shtw3[NB], shb3[NB];
    __shared__ unsigned char sli[NT], sqv[NT];
    __shared__ float stv[NT];
    __shared__ float sout[NT];
    __shared__ int scnt[NB + 1], sbase[NB + 1];
    __shared__ __align__(16) unsigned char hbuf[4][2][2][2048]; // [wave][tile-in-pair][A/B]

    const int tid = threadIdx.x;
    const int lane = tid & 63;
    const int wv = tid >> 6;
    const int g = lane >> 4;
    const int row = lane & 15;

    for (int p = tid; p < H; p += NT) { sb1f[p] = db1[p]; sb2f[p] = db2[p]; }
    for (int p = tid; p < NB * H; p += NT) {
        shb1[p] = hb1[p];  shw1t[p] = htw1[p];
        shb2[p] = hb2[p];  shw2t[p] = htw2[p];
        sw3f[p] = hw3[p];
    }
    if (tid < NB) { shtw3[tid] = htw3[tid]; shb3[tid] = hb3[tid]; }

    // trunk weight frags resident in registers (48 VGPR) — launch_bounds(·,2)
    // gives the 256-VGPR budget so these MUST NOT spill (round-3 lesson).
    f16x8 w1f[16], w2f[8];
    #pragma unroll
    for (int u = 0; u < 16; ++u) w1f[u] = pw[FR_W1 + u * 64 + lane];
    #pragma unroll
    for (int u = 0; u < 8; ++u)  w2f[u] = pw[FR_W2 + u * 64 + lane];

    // prefetch this block's first chunk of t
    float tpre = 0.f;
    {
        int i0 = blockIdx.x * NT + tid;
        if (blockIdx.x < nch && i0 < N) tpre = t[i0];
    }

    for (int ch = blockIdx.x; ch < nch; ch += MAIN_BLOCKS) {
        if (tid <= NB) scnt[tid] = 0;
        __syncthreads();
        const int i0 = ch * NT + tid;
        const float tv0 = tpre;
        int q0 = NB;
        if (i0 < N) q0 = min((int)(tv0 * 5.0f), NB - 1);  // t in [0,1): trunc==floor
        int pos = atomicAdd(&scnt[q0], 1);
        __syncthreads();
        if (tid == 0) {
            int r = 0;
            #pragma unroll
            for (int b = 0; b <= NB; ++b) { sbase[b] = r; r += scnt[b]; }
        }
        __syncthreads();
        int sp = sbase[q0] + pos;
        sli[sp] = (unsigned char)tid; sqv[sp] = (unsigned char)q0; stv[sp] = tv0;
        __syncthreads();

        // issue next chunk's t load now — hides under this chunk's compute
        {
            int inx = (ch + MAIN_BLOCKS) * NT + tid;
            tpre = (ch + MAIN_BLOCKS < nch && inx < N) ? t[inx] : 0.f;
        }

        // wave wv owns sorted tiles 4wv..4wv+3, processed as 2 pairs of 2
        for (int j = 0; j < 2; ++j) {
            const int pA = (wv * 4 + 2 * j) * 16;
            const int pB = pA + 16;
            const int qloA = sqv[pA];
            const int qloB = sqv[pB];
            const int liA = sli[pA + row], liB = sli[pB + row];
            const int rqA = sqv[pA + row], rqB = sqv[pB + row];
            const float rtA = stv[pA + row], rtB = stv[pB + row];
            const int ivA = (rqA < NB) ? (ch * NT + liA) : (ch * NT);
            const int ivB = (rqB < NB) ? (ch * NT + liB) : (ch * NT);

            // issue BOTH tiles' x loads back-to-back (latencies overlap)
            float4 xrA[7], xrB[7];
            {
                const float4* x4 = (const float4*)(x + (size_t)ivA * DIN);
                #pragma unroll
                for (int s = 0; s < 3; ++s) { xrA[2*s] = x4[8*s + 2*g]; xrA[2*s+1] = x4[8*s + 2*g + 1]; }
                xrA[6] = x4[24];
            }
            {
                const float4* x4 = (const float4*)(x + (size_t)ivB * DIN);
                #pragma unroll
                for (int s = 0; s < 3; ++s) { xrB[2*s] = x4[8*s + 2*g]; xrB[2*s+1] = x4[8*s + 2*g + 1]; }
                xrB[6] = x4[24];
            }

            if (qloA >= NB) continue;   // whole pair is padding (sorted => B too)

            // convert to A-frags
            f16x8 xfA[4], xfB[4];
            #pragma unroll
            for (int s = 0; s < 3; ++s) {
                float4 a = xrA[2*s], b = xrA[2*s+1];
                xfA[s][0]=(f16)a.x; xfA[s][1]=(f16)a.y; xfA[s][2]=(f16)a.z; xfA[s][3]=(f16)a.w;
                xfA[s][4]=(f16)b.x; xfA[s][5]=(f16)b.y; xfA[s][6]=(f16)b.z; xfA[s][7]=(f16)b.w;
                float4 c = xrB[2*s], d = xrB[2*s+1];
                xfB[s][0]=(f16)c.x; xfB[s][1]=(f16)c.y; xfB[s][2]=(f16)c.z; xfB[s][3]=(f16)c.w;
                xfB[s][4]=(f16)d.x; xfB[s][5]=(f16)d.y; xfB[s][6]=(f16)d.z; xfB[s][7]=(f16)d.w;
            }
            {
                const bool lo = (g == 0);
                float4 a = xrA[6], b = xrB[6];
                xfA[3][0]=lo?(f16)a.x:(f16)0.f; xfA[3][1]=lo?(f16)a.y:(f16)0.f;
                xfA[3][2]=lo?(f16)a.z:(f16)0.f; xfA[3][3]=lo?(f16)a.w:(f16)0.f;
                xfA[3][4]=(f16)0.f; xfA[3][5]=(f16)0.f; xfA[3][6]=(f16)0.f; xfA[3][7]=(f16)0.f;
                xfB[3][0]=lo?(f16)b.x:(f16)0.f; xfB[3][1]=lo?(f16)b.y:(f16)0.f;
                xfB[3][2]=lo?(f16)b.z:(f16)0.f; xfB[3][3]=lo?(f16)b.w:(f16)0.f;
                xfB[3][4]=(f16)0.f; xfB[3][5]=(f16)0.f; xfB[3][6]=(f16)0.f; xfB[3][7]=(f16)0.f;
            }

            const f32x4 zero = {0.f, 0.f, 0.f, 0.f};
            unsigned char* hA_A = hbuf[wv][0][0];
            unsigned char* hB_A = hbuf[wv][0][1];
            unsigned char* hA_B = hbuf[wv][1][0];
            unsigned char* hB_B = hbuf[wv][1][1];

            // ---- trunk L1 (both tiles interleaved; w-frag shared) ----
            f32x4 accA[4] = {zero, zero, zero, zero};
            f32x4 accB[4] = {zero, zero, zero, zero};
            #pragma unroll
            for (int s = 0; s < 4; ++s)
                #pragma unroll
                for (int mt = 0; mt < 4; ++mt) {
                    accA[mt] = mfma16(w1f[s * 4 + mt], xfA[s], accA[mt]);
                    accB[mt] = mfma16(w1f[s * 4 + mt], xfB[s], accB[mt]);
                }
            epi_plain(hA_A, row, g, accA, sb1f);
            epi_plain(hA_B, row, g, accB, sb1f);

            // ---- trunk L2 ----
            f32x4 acc2A[4] = {zero, zero, zero, zero};
            f32x4 acc2B[4] = {zero, zero, zero, zero};
            #pragma unroll
            for (int s = 0; s < 2; ++s) {
                f16x8 hfA = lds_read_h(hA_A, row, g, s);
                f16x8 hfB = lds_read_h(hA_B, row, g, s);
                #pragma unroll
                for (int mt = 0; mt < 4; ++mt) {
                    acc2A[mt] = mfma16(w2f[s * 4 + mt], hfA, acc2A[mt]);
                    acc2B[mt] = mfma16(w2f[s * 4 + mt], hfB, acc2B[mt]);
                }
            }
            epi_plain(hB_A, row, g, acc2A, sb2f);
            epi_plain(hB_B, row, g, acc2B, sb2f);

            // ---- heads over union range (tiles sorted: qloA <= qloB) ----
            const int qhiA = min((int)sqv[pA + 15], NB - 1);
            int qhi = qhiA;
            if (qloB < NB) qhi = max(qhi, min((int)sqv[pB + 15], NB - 1));

            #pragma unroll 1
            for (int q = qloA; q <= qhi; ++q) {
                const f16x8* ph1 = pw + FR_HD + (q * 2 + 0) * 512;
                const f16x8* ph2 = pw + FR_HD + (q * 2 + 1) * 512;

                f32x4 a1A[4] = {zero, zero, zero, zero};
                f32x4 a1B[4] = {zero, zero, zero, zero};
                #pragma unroll
                for (int s = 0; s < 2; ++s) {
                    f16x8 hfA = lds_read_h(hB_A, row, g, s);
                    f16x8 hfB = lds_read_h(hB_B, row, g, s);
                    #pragma unroll
                    for (int mt = 0; mt < 4; ++mt) {
                        f16x8 wf = ph1[(s * 4 + mt) * 64 + lane];
                        a1A[mt] = mfma16(wf, hfA, a1A[mt]);
                        a1B[mt] = mfma16(wf, hfB, a1B[mt]);
                    }
                }
                epi_t(hA_A, row, g, rtA, a1A, &shb1[q * 64], &shw1t[q * 64]);
                epi_t(hA_B, row, g, rtB, a1B, &shb1[q * 64], &shw1t[q * 64]);

                f32x4 a2A[4] = {zero, zero, zero, zero};
                f32x4 a2B[4] = {zero, zero, zero, zero};
                #pragma unroll
                for (int s = 0; s < 2; ++s) {
                    f16x8 hfA = lds_read_h(hA_A, row, g, s);
                    f16x8 hfB = lds_read_h(hA_B, row, g, s);
                    #pragma unroll
                    for (int mt = 0; mt < 4; ++mt) {
                        f16x8 wf = ph2[(s * 4 + mt) * 64 + lane];
                        a2A[mt] = mfma16(wf, hfA, a2A[mt]);
                        a2B[mt] = mfma16(wf, hfB, a2B[mt]);
                    }
                }

                float pa = 0.f, pb = 0.f;
                #pragma unroll
                for (int mt = 0; mt < 4; ++mt) {
                    const float* bb = &shb2[q * 64 + 16 * mt + 4 * g];
                    const float* tw = &shw2t[q * 64 + 16 * mt + 4 * g];
                    const float* w3 = &sw3f[q * 64 + 16 * mt + 4 * g];
                    #pragma unroll
                    for (int r2 = 0; r2 < 4; ++r2) {
                        float vA = fmaxf(a2A[mt][r2] + bb[r2] + rtA * tw[r2], 0.f);
                        float vB = fmaxf(a2B[mt][r2] + bb[r2] + rtB * tw[r2], 0.f);
                        pa += vA * w3[r2];
                        pb += vB * w3[r2];
                    }
                }
                pa += __shfl_xor(pa, 16, 64);
                pa += __shfl_xor(pa, 32, 64);
                pb += __shfl_xor(pb, 16, 64);
                pb += __shfl_xor(pb, 32, 64);
                if (lane < 16) {
                    if (rqA == q) sout[liA] = pa + rtA * shtw3[q] + shb3[q];
                    if (rqB == q) sout[liB] = pb + rtB * shtw3[q] + shb3[q];
                }
            }
        }

        __syncthreads();                 // sout complete across all waves
        {
            const int iw = ch * NT + tid;
            if (iw < N) out[iw] = sout[tid];   // coalesced flush
        }
    }
}

extern "C" void kernel_launch(void* const* d_in, const int* in_sizes, int n_in,
                              void* d_out, int out_size, void* d_ws, size_t ws_size,
                              hipStream_t stream) {
    const float* t    = (const float*)d_in[0];
    const float* x    = (const float*)d_in[1];
    const float* dW1  = (const float*)d_in[2];
    const float* db1  = (const float*)d_in[3];
    const float* dW2  = (const float*)d_in[4];
    const float* db2  = (const float*)d_in[5];
    const float* hw1  = (const float*)d_in[6];
    const float* htw1 = (const float*)d_in[7];
    const float* hb1  = (const float*)d_in[8];
    const float* hw2  = (const float*)d_in[9];
    const float* htw2 = (const float*)d_in[10];
    const float* hb2  = (const float*)d_in[11];
    const float* hw3  = (const float*)d_in[12];
    const float* htw3 = (const float*)d_in[13];
    const float* hb3  = (const float*)d_in[14];
    float* out = (float*)d_out;

    const int N = in_sizes[0];
    const int nch = (N + NT - 1) / NT;
    f16x8* pw = (f16x8*)d_ws;   // 6656 * 16 B = 104 KiB of scratch

    prepack_kernel<<<(FR_TOT + 255) / 256, 256, 0, stream>>>(dW1, dW2, hw1, hw2, pw);
    drnet_main<<<MAIN_BLOCKS, NT, 0, stream>>>(t, x, db1, db2, hb1, htw1, hb2, htw2,
                                               hw3, htw3, hb3, pw, out, N, nch);
}

// Round 5
// 157.037 us; speedup vs baseline: 1.3716x; 1.0227x over previous
//
#include <hip/hip_runtime.h>

typedef _Float16 f16;
typedef _Float16 f16x8 __attribute__((ext_vector_type(8)));
typedef float f32x4 __attribute__((ext_vector_type(4)));

#define NB 5
#define H 64
#define DIN 100
#define NT 256
#define MAIN_BLOCKS 512

// packed weight-fragment regions in d_ws, units of 16B frags
#define FR_W1   0      // 4 ksteps * 4 mtiles * 64 lanes = 1024 frags
#define FR_W2   1024   // 2 * 4 * 64 = 512
#define FR_HD   1536   // (q*2+layer)*512 + (s*4+mt)*64 + lane ; 5*2*512 = 5120
#define FR_TOT  6656
#define FR_TRUNK 1536  // W1+W2 frags staged to LDS per block

// Pack weights into MFMA A-operand fragment layout for the transposed compute:
// A = W^T tile: lane l holds W[k=32s+8*(l>>4)+e][16*mt + (l&15)], e=0..7.
__global__ __launch_bounds__(256)
void prepack_kernel(const float* __restrict__ dW1, const float* __restrict__ dW2,
                    const float* __restrict__ hw1, const float* __restrict__ hw2,
                    f16x8* __restrict__ pw)
{
    int F = blockIdx.x * 256 + threadIdx.x;
    if (F >= FR_TOT) return;
    int lane = F & 63, g = lane >> 4, c = lane & 15;
    const float* src;
    int s, mt, kmax;
    if (F < FR_W2) {                       // trunk W1 [100][64], zero-pad K to 128
        int r = F; s = r >> 8; mt = (r >> 6) & 3; src = dW1; kmax = 100;
    } else if (F < FR_HD) {                // trunk W2 [64][64]
        int r = F - FR_W2; s = r >> 8; mt = (r >> 6) & 3; src = dW2; kmax = 64;
    } else {                               // heads hw1/hw2 [5][64][64]
        int r = F - FR_HD; int ql = r >> 9; int q = ql >> 1; int l = ql & 1;
        int r2 = r & 511; s = r2 >> 8; mt = (r2 >> 6) & 3;
        src = (l ? hw2 : hw1) + q * 64 * 64; kmax = 64;
    }
    f16x8 v;
    #pragma unroll
    for (int e = 0; e < 8; ++e) {
        int k = 32 * s + 8 * g + e;
        int m = 16 * mt + c;
        float val = (k < kmax) ? src[k * 64 + m] : 0.0f;
        v[e] = (f16)val;
    }
    pw[F] = v;
}

struct XF { f16x8 v[4]; };

__device__ __forceinline__ f32x4 mfma16(f16x8 a, f16x8 b, f32x4 c) {
    return __builtin_amdgcn_mfma_f32_16x16x32_f16(a, b, c, 0, 0, 0);
}

// trunk weight frag from LDS (contiguous lane*16 -> conflict-free b128)
__device__ __forceinline__ f16x8 ldw(const unsigned char* swf, int idx) {
    return *(const f16x8*)(swf + (idx << 4));
}

__device__ __forceinline__ void load_tile(float4* xr, const float* x, int iv, int g) {
    const float4* x4 = (const float4*)(x + (size_t)iv * DIN);  // rows 16B-aligned (400=25*16)
    #pragma unroll
    for (int s = 0; s < 3; ++s) { xr[2*s] = x4[8*s + 2*g]; xr[2*s+1] = x4[8*s + 2*g + 1]; }
    xr[6] = x4[24];
}

__device__ __forceinline__ void conv_tile(XF& xf, const float4* xr, int g) {
    #pragma unroll
    for (int s = 0; s < 3; ++s) {
        float4 a = xr[2*s], b = xr[2*s+1];
        xf.v[s][0]=(f16)a.x; xf.v[s][1]=(f16)a.y; xf.v[s][2]=(f16)a.z; xf.v[s][3]=(f16)a.w;
        xf.v[s][4]=(f16)b.x; xf.v[s][5]=(f16)b.y; xf.v[s][6]=(f16)b.z; xf.v[s][7]=(f16)b.w;
    }
    {
        const bool lo = (g == 0);          // k=96..99 valid only for g==0
        float4 a = xr[6];
        xf.v[3][0]=lo?(f16)a.x:(f16)0.f; xf.v[3][1]=lo?(f16)a.y:(f16)0.f;
        xf.v[3][2]=lo?(f16)a.z:(f16)0.f; xf.v[3][3]=lo?(f16)a.w:(f16)0.f;
        xf.v[3][4]=(f16)0.f; xf.v[3][5]=(f16)0.f; xf.v[3][6]=(f16)0.f; xf.v[3][7]=(f16)0.f;
    }
}

// relu(acc + bias) -> f16x4, XOR-swizzled b64 store into per-wave LDS h-buffer
__device__ __forceinline__ void epi_plain(unsigned char* buf, int row, int g,
                                          const f32x4* acc, const float* bias) {
    #pragma unroll
    for (int mt = 0; mt < 4; ++mt) {
        const float* bb = &bias[16 * mt + 4 * g];
        union { f16 h[4]; unsigned long long u; } pk;
        #pragma unroll
        for (int r2 = 0; r2 < 4; ++r2) pk.h[r2] = (f16)fmaxf(acc[mt][r2] + bb[r2], 0.f);
        *(unsigned long long*)(buf + ((row * 128 + 32 * mt + 8 * g) ^ ((row & 7) << 4))) = pk.u;
    }
}

// relu(acc + bias + rt*tw) -> f16x4, swizzled store
__device__ __forceinline__ void epi_t(unsigned char* buf, int row, int g, float rt,
                                      const f32x4* acc, const float* bias, const float* tw) {
    #pragma unroll
    for (int mt = 0; mt < 4; ++mt) {
        const float* bb = &bias[16 * mt + 4 * g];
        const float* tt = &tw[16 * mt + 4 * g];
        union { f16 h[4]; unsigned long long u; } pk;
        #pragma unroll
        for (int r2 = 0; r2 < 4; ++r2)
            pk.h[r2] = (f16)fmaxf(acc[mt][r2] + bb[r2] + rt * tt[r2], 0.f);
        *(unsigned long long*)(buf + ((row * 128 + 32 * mt + 8 * g) ^ ((row & 7) << 4))) = pk.u;
    }
}

__device__ __forceinline__ f16x8 lds_read_h(const unsigned char* buf, int row, int g, int s) {
    return *(const f16x8*)(buf + ((row * 128 + 64 * s + 16 * g) ^ ((row & 7) << 4)));
}

__global__ __launch_bounds__(NT, 2)
void drnet_main(const float* __restrict__ t, const float* __restrict__ x,
                const float* __restrict__ db1, const float* __restrict__ db2,
                const float* __restrict__ hb1, const float* __restrict__ htw1,
                const float* __restrict__ hb2, const float* __restrict__ htw2,
                const float* __restrict__ hw3, const float* __restrict__ htw3,
                const float* __restrict__ hb3,
                const f16x8* __restrict__ pw,
                float* __restrict__ out, int N, int nch)
{
    __shared__ float sb1f[H], sb2f[H];
    __shared__ float shb1[NB * H], shw1t[NB * H], shb2[NB * H], shw2t[NB * H], sw3f[NB * H];
    __shared__ float shtw3[NB], shb3[NB];
    __shared__ unsigned char sli[NT], sqv[NT];
    __shared__ float stv[NT];
    __shared__ float sout[NT];
    __shared__ int scnt[NB + 1], sbase[NB + 1];
    __shared__ __align__(16) unsigned char swf[FR_TRUNK * 16];   // 24.5 KB trunk weight frags
    __shared__ __align__(16) unsigned char hbuf[4][2][2][2048];  // [wave][tile-in-pair][A/B]

    const int tid = threadIdx.x;
    const int lane = tid & 63;
    const int wv = tid >> 6;
    const int g = lane >> 4;
    const int row = lane & 15;

    for (int p = tid; p < H; p += NT) { sb1f[p] = db1[p]; sb2f[p] = db2[p]; }
    for (int p = tid; p < NB * H; p += NT) {
        shb1[p] = hb1[p];  shw1t[p] = htw1[p];
        shb2[p] = hb2[p];  shw2t[p] = htw2[p];
        sw3f[p] = hw3[p];
    }
    if (tid < NB) { shtw3[tid] = htw3[tid]; shb3[tid] = hb3[tid]; }
    // trunk weight frags -> LDS (frees ~96 VGPR vs register hoisting; round-3/4 lesson)
    for (int p = tid; p < FR_TRUNK; p += NT)
        ((float4*)swf)[p] = ((const float4*)pw)[p];

    // prefetch this block's first chunk of t
    float tpre = 0.f;
    {
        int i0 = blockIdx.x * NT + tid;
        if (blockIdx.x < nch && i0 < N) tpre = t[i0];
    }

    auto compute_pair = [&](const XF& xfA, const XF& xfB, int pA) {
        const int qloA = sqv[pA];
        if (qloA >= NB) return;                   // whole pair padding (sorted)
        const int pB = pA + 16;
        const int qloB = sqv[pB];
        const int liA = sli[pA + row], liB = sli[pB + row];
        const int rqA = sqv[pA + row], rqB = sqv[pB + row];
        const float rtA = stv[pA + row], rtB = stv[pB + row];

        const f32x4 zero = {0.f, 0.f, 0.f, 0.f};
        unsigned char* hA_A = hbuf[wv][0][0];
        unsigned char* hB_A = hbuf[wv][0][1];
        unsigned char* hA_B = hbuf[wv][1][0];
        unsigned char* hB_B = hbuf[wv][1][1];

        // ---- trunk L1 (weights from LDS; both tiles share each frag) ----
        f32x4 accA[4] = {zero, zero, zero, zero};
        f32x4 accB[4] = {zero, zero, zero, zero};
        #pragma unroll
        for (int s = 0; s < 4; ++s)
            #pragma unroll
            for (int mt = 0; mt < 4; ++mt) {
                f16x8 wf = ldw(swf, FR_W1 + (s * 4 + mt) * 64 + lane);
                accA[mt] = mfma16(wf, xfA.v[s], accA[mt]);
                accB[mt] = mfma16(wf, xfB.v[s], accB[mt]);
            }
        epi_plain(hA_A, row, g, accA, sb1f);
        epi_plain(hA_B, row, g, accB, sb1f);

        // ---- trunk L2 ----
        f32x4 acc2A[4] = {zero, zero, zero, zero};
        f32x4 acc2B[4] = {zero, zero, zero, zero};
        #pragma unroll
        for (int s = 0; s < 2; ++s) {
            f16x8 hfA = lds_read_h(hA_A, row, g, s);
            f16x8 hfB = lds_read_h(hA_B, row, g, s);
            #pragma unroll
            for (int mt = 0; mt < 4; ++mt) {
                f16x8 wf = ldw(swf, FR_W2 + (s * 4 + mt) * 64 + lane);
                acc2A[mt] = mfma16(wf, hfA, acc2A[mt]);
                acc2B[mt] = mfma16(wf, hfB, acc2B[mt]);
            }
        }
        epi_plain(hB_A, row, g, acc2A, sb2f);
        epi_plain(hB_B, row, g, acc2B, sb2f);

        // ---- heads over union range (tiles sorted: qloA <= qloB) ----
        const int qhiA = min((int)sqv[pA + 15], NB - 1);
        int qhi = qhiA;
        if (qloB < NB) qhi = max(qhi, min((int)sqv[pB + 15], NB - 1));

        #pragma unroll 1
        for (int q = qloA; q <= qhi; ++q) {
            const f16x8* ph1 = pw + FR_HD + (q * 2 + 0) * 512;
            const f16x8* ph2 = pw + FR_HD + (q * 2 + 1) * 512;

            f32x4 a1A[4] = {zero, zero, zero, zero};
            f32x4 a1B[4] = {zero, zero, zero, zero};
            #pragma unroll
            for (int s = 0; s < 2; ++s) {
                f16x8 hfA = lds_read_h(hB_A, row, g, s);
                f16x8 hfB = lds_read_h(hB_B, row, g, s);
                #pragma unroll
                for (int mt = 0; mt < 4; ++mt) {
                    f16x8 wf = ph1[(s * 4 + mt) * 64 + lane];
                    a1A[mt] = mfma16(wf, hfA, a1A[mt]);
                    a1B[mt] = mfma16(wf, hfB, a1B[mt]);
                }
            }
            epi_t(hA_A, row, g, rtA, a1A, &shb1[q * 64], &shw1t[q * 64]);
            epi_t(hA_B, row, g, rtB, a1B, &shb1[q * 64], &shw1t[q * 64]);

            f32x4 a2A[4] = {zero, zero, zero, zero};
            f32x4 a2B[4] = {zero, zero, zero, zero};
            #pragma unroll
            for (int s = 0; s < 2; ++s) {
                f16x8 hfA = lds_read_h(hA_A, row, g, s);
                f16x8 hfB = lds_read_h(hA_B, row, g, s);
                #pragma unroll
                for (int mt = 0; mt < 4; ++mt) {
                    f16x8 wf = ph2[(s * 4 + mt) * 64 + lane];
                    a2A[mt] = mfma16(wf, hfA, a2A[mt]);
                    a2B[mt] = mfma16(wf, hfB, a2B[mt]);
                }
            }

            float pa = 0.f, pb = 0.f;
            #pragma unroll
            for (int mt = 0; mt < 4; ++mt) {
                const float* bb = &shb2[q * 64 + 16 * mt + 4 * g];
                const float* tw = &shw2t[q * 64 + 16 * mt + 4 * g];
                const float* w3 = &sw3f[q * 64 + 16 * mt + 4 * g];
                #pragma unroll
                for (int r2 = 0; r2 < 4; ++r2) {
                    float vA = fmaxf(a2A[mt][r2] + bb[r2] + rtA * tw[r2], 0.f);
                    float vB = fmaxf(a2B[mt][r2] + bb[r2] + rtB * tw[r2], 0.f);
                    pa += vA * w3[r2];
                    pb += vB * w3[r2];
                }
            }
            pa += __shfl_xor(pa, 16, 64);
            pa += __shfl_xor(pa, 32, 64);
            pb += __shfl_xor(pb, 16, 64);
            pb += __shfl_xor(pb, 32, 64);
            if (lane < 16) {
                if (rqA == q) sout[liA] = pa + rtA * shtw3[q] + shb3[q];
                if (rqB == q) sout[liB] = pb + rtB * shtw3[q] + shb3[q];
            }
        }
    };

    for (int ch = blockIdx.x; ch < nch; ch += MAIN_BLOCKS) {
        if (tid <= NB) scnt[tid] = 0;
        __syncthreads();
        const int i0 = ch * NT + tid;
        const float tv0 = tpre;
        int q0 = NB;
        if (i0 < N) q0 = min((int)(tv0 * 5.0f), NB - 1);  // t in [0,1): trunc==floor
        int pos = atomicAdd(&scnt[q0], 1);
        __syncthreads();
        if (tid == 0) {
            int r = 0;
            #pragma unroll
            for (int b = 0; b <= NB; ++b) { sbase[b] = r; r += scnt[b]; }
        }
        __syncthreads();
        int sp = sbase[q0] + pos;
        sli[sp] = (unsigned char)tid; sqv[sp] = (unsigned char)q0; stv[sp] = tv0;
        __syncthreads();

        // issue next chunk's t load now — hides under this chunk's compute
        {
            int inx = (ch + MAIN_BLOCKS) * NT + tid;
            tpre = (ch + MAIN_BLOCKS < nch && inx < N) ? t[inx] : 0.f;
        }

        // ---- issue ALL 4 tiles' x loads up front: ~28KB/wave stays in flight
        //      while pair 0 computes (outstanding-request depth is the bottleneck)
        const int tb = wv * 64;
        int ivs[4];
        #pragma unroll
        for (int m = 0; m < 4; ++m) {
            int pm = tb + m * 16 + row;
            ivs[m] = (sqv[pm] < NB) ? (ch * NT + sli[pm]) : (ch * NT);
        }
        float4 xr0[7], xr1[7], xr2[7], xr3[7];
        load_tile(xr0, x, ivs[0], g);
        load_tile(xr1, x, ivs[1], g);
        load_tile(xr2, x, ivs[2], g);
        load_tile(xr3, x, ivs[3], g);

        XF xfA, xfB;
        conv_tile(xfA, xr0, g);          // waits only on tiles 0-1's loads;
        conv_tile(xfB, xr1, g);          // tiles 2-3 stay outstanding
        compute_pair(xfA, xfB, tb);
        conv_tile(xfA, xr2, g);
        conv_tile(xfB, xr3, g);
        compute_pair(xfA, xfB, tb + 32);

        __syncthreads();                 // sout complete across all waves
        {
            const int iw = ch * NT + tid;
            if (iw < N) out[iw] = sout[tid];   // coalesced flush
        }
    }
}

extern "C" void kernel_launch(void* const* d_in, const int* in_sizes, int n_in,
                              void* d_out, int out_size, void* d_ws, size_t ws_size,
                              hipStream_t stream) {
    const float* t    = (const float*)d_in[0];
    const float* x    = (const float*)d_in[1];
    const float* dW1  = (const float*)d_in[2];
    const float* db1  = (const float*)d_in[3];
    const float* dW2  = (const float*)d_in[4];
    const float* db2  = (const float*)d_in[5];
    const float* hw1  = (const float*)d_in[6];
    const float* htw1 = (const float*)d_in[7];
    const float* hb1  = (const float*)d_in[8];
    const float* hw2  = (const float*)d_in[9];
    const float* htw2 = (const float*)d_in[10];
    const float* hb2  = (const float*)d_in[11];
    const float* hw3  = (const float*)d_in[12];
    const float* htw3 = (const float*)d_in[13];
    const float* hb3  = (const float*)d_in[14];
    float* out = (float*)d_out;

    const int N = in_sizes[0];
    const int nch = (N + NT - 1) / NT;
    f16x8* pw = (f16x8*)d_ws;   // 6656 * 16 B = 104 KiB of scratch

    prepack_kernel<<<(FR_TOT + 255) / 256, 256, 0, stream>>>(dW1, dW2, hw1, hw2, pw);
    drnet_main<<<MAIN_BLOCKS, NT, 0, stream>>>(t, x, db1, db2, hb1, htw1, hb2, htw2,
                                               hw3, htw3, hb3, pw, out, N, nch);
}